// Round 8
// baseline (239.072 us; speedup 1.0000x reference)
//
#include <hip/hip_runtime.h>

#define VGRID 256
#define N_TAPS 27
#define CIN 64
#define COUT 64
#define BPTS 64      // points per chunk (1 group of 16 per wave, 4 waves)
#define HBITS 20
#define HSIZE (1u << HBITS)          // 1M slots x 8 B = 8 MiB hash
#define HEMPTY 0xFFFFFFFFFFFFFFFFull // memset 0xFF => empty

typedef short short8 __attribute__((ext_vector_type(8)));   // 8 bf16
typedef float float4v __attribute__((ext_vector_type(4)));  // MFMA C/D + NT loads

__device__ __forceinline__ short f2bf(float x) {
    unsigned u = __builtin_bit_cast(unsigned, x);
    unsigned r = (u + 0x7FFF + ((u >> 16) & 1)) >> 16;  // RNE
    return (short)r;
}

__device__ __forceinline__ unsigned hslot(int lin) {
    return ((unsigned)lin * 2654435761u) >> (32 - HBITS);
}

// walk from slot s for a voxel KNOWN to exist (bitmap-gated)
__device__ __forceinline__ int hwalk(const unsigned long long* __restrict__ hash,
                                     int lin, unsigned s) {
    for (;;) {
        unsigned long long e = hash[s];
        if ((unsigned)(e >> 32) == (unsigned)lin) return (int)(unsigned)e;
        s = (s + 1) & (HSIZE - 1);
    }
}

__device__ __forceinline__ int hlookup(const unsigned long long* __restrict__ hash,
                                       int lin) {
    return hwalk(hash, lin, hslot(lin));
}

// hash insert + bitmap (1024 blocks) — split out for rocprof visibility
__global__ void __launch_bounds__(256) build_scatter(
        const int* __restrict__ coords, unsigned long long* __restrict__ hash,
        unsigned* __restrict__ bits, int n) {
    int i = blockIdx.x * 256 + threadIdx.x;
    if (i >= n) return;
    int lin = (coords[i * 3 + 0] * VGRID + coords[i * 3 + 1]) * VGRID + coords[i * 3 + 2];
    // insert (lin -> i); duplicates keep max i (== ref last-write-wins since
    // high words equal, u64 atomicMax compares low words)
    unsigned long long want = ((unsigned long long)(unsigned)lin << 32) | (unsigned)i;
    unsigned s = hslot(lin);
    for (;;) {
        unsigned long long old = atomicCAS(&hash[s], HEMPTY, want);
        if (old == HEMPTY) break;
        if ((unsigned)(old >> 32) == (unsigned)lin) { atomicMax(&hash[s], want); break; }
        s = (s + 1) & (HSIZE - 1);
    }
    atomicOr(&bits[lin >> 5], 1u << (lin & 31));
}

// blocks [0,27): weight conversion to fragment-major bf16
// blocks [27,...): feats f32 -> bf16, 16 floats/thread, NT loads + NT stores
// (contiguous full-line NT stores; the R6 amplification was scattered 4B NT)
__global__ void __launch_bounds__(256) build_convert(
        const float* __restrict__ W, short* __restrict__ Wt,
        const float* __restrict__ F, short* __restrict__ Fb, int fb_elems) {
    int b = (int)blockIdx.x;
    if (b < N_TAPS) {
        int tap = b;
        for (int e = threadIdx.x; e < CIN * COUT; e += 256) {
            int ci = e >> 6, co = e & 63;
            int ks = ci >> 5, quad = (ci >> 3) & 3, el = ci & 7;
            Wt[((((size_t)tap * 2 + ks) * 4 + quad) * 64 + co) * 8 + el] =
                f2bf(W[((size_t)tap * CIN + ci) * COUT + co]);
        }
        return;
    }
    int idx = (b - N_TAPS) * 256 + (int)threadIdx.x;
    int e = idx * 16;
    if (e < fb_elems) {
        const float4v* s = (const float4v*)(F + e);
        float4v x0 = __builtin_nontemporal_load(s);
        float4v x1 = __builtin_nontemporal_load(s + 1);
        float4v x2 = __builtin_nontemporal_load(s + 2);
        float4v x3 = __builtin_nontemporal_load(s + 3);
        short8 o0 = {f2bf(x0[0]), f2bf(x0[1]), f2bf(x0[2]), f2bf(x0[3]),
                     f2bf(x1[0]), f2bf(x1[1]), f2bf(x1[2]), f2bf(x1[3])};
        short8 o1 = {f2bf(x2[0]), f2bf(x2[1]), f2bf(x2[2]), f2bf(x2[3]),
                     f2bf(x3[0]), f2bf(x3[1]), f2bf(x3[2]), f2bf(x3[3])};
        __builtin_nontemporal_store(o0, (short8*)(Fb + e));
        __builtin_nontemporal_store(o1, (short8*)(Fb + e + 8));
    }
}

// Persistent 2-chunk gather conv: block handles chunks b and b+gridDim
// (64 points each). Chunk-1's independent probe loads (coords, bitmap words,
// speculative first center-hash probe) are issued BEFORE chunk-0's GEMM and
// consumed after -> chunk-1 probe latency hides under chunk-0 compute.
// Per chunk: R7 structure (4-way split probe, rank-q prefetch, 16-row MFMA
// group per wave, regular stores).
__global__ void __launch_bounds__(256) fused_kernel(
        const int* __restrict__ coords, const unsigned long long* __restrict__ hash,
        const unsigned* __restrict__ bits, const short* __restrict__ featsb,
        const short* __restrict__ Wt, float* __restrict__ out, int n) {
    __shared__ int s_pk[2][BPTS];
    __shared__ unsigned s_hm[2][4][BPTS];
    __shared__ int s_jc[2][BPTS];
    __shared__ int s_p[2][4][BPTS];

    int t = threadIdx.x;
    int p = t & (BPTS - 1);
    int q = t >> 6;                      // quarter == wave index
    int lane = t & 63;
    int m = lane & 15, quad = lane >> 4;
    const short8* Bp = (const short8*)Wt;
    const short8* Fp = (const short8*)featsb;   // 16B units; row j = 8 units

    // ---- probe-load issue (pure loads, no LDS) ----
    auto issue = [&](int i, int& cx, int& cy, int& cz,
                     unsigned (&wa)[3], unsigned (&wb)[3],
                     unsigned long long& e0, unsigned& s0) {
        cx = 0; cy = 0; cz = 0; e0 = 0; s0 = 0;
#pragma unroll
        for (int rr = 0; rr < 3; ++rr) { wa[rr] = 0u; wb[rr] = 0u; }
        if (i < n) {
            cx = coords[i * 3 + 0];
            cy = coords[i * 3 + 1];
            cz = coords[i * 3 + 2];
            if (q == 0) {               // speculative first center probe
                s0 = hslot((cx * VGRID + cy) * VGRID + cz);
                e0 = hash[s0];
            }
            int zlo = cz > 0 ? cz - 1 : 0;
            int zhi = cz < VGRID - 1 ? cz + 1 : VGRID - 1;
            int wlo = zlo >> 5, whi = zhi >> 5;
            int nr = (q == 3) ? 3 : 2;
            int r0 = 2 * q;
#pragma unroll
            for (int rr = 0; rr < 3; ++rr) {
                int r = r0 + rr;
                int nx = cx + r / 3 - 1, ny = cy + r % 3 - 1;
                bool v = (rr < nr) && ((unsigned)nx < VGRID) && ((unsigned)ny < VGRID);
                int rb = ((nx * VGRID + ny) * VGRID) >> 5;  // row base word (%32==0)
                wa[rr] = v ? bits[rb + wlo] : 0u;
                wb[rr] = v ? bits[rb + whi] : 0u;
            }
        }
    };

    // ---- probe finish: masks -> LDS; resolve center j (q0) ----
    auto finish = [&](int c, int i, int cx, int cy, int cz,
                      unsigned (&wa)[3], unsigned (&wb)[3],
                      unsigned long long e0, unsigned s0) {
        unsigned pmask = 0;
        if (i < n) {
            int zlo = cz > 0 ? cz - 1 : 0;
            int wlo = zlo >> 5;
            int nr = (q == 3) ? 3 : 2;
            int r0 = 2 * q;
#pragma unroll
            for (int rr = 0; rr < 3; ++rr) {
                int r = r0 + rr;
#pragma unroll
                for (int zz = 0; zz < 3; ++zz) {
                    int k = r * 3 + zz;
                    int nz = cz + zz - 1;
                    if (rr < nr && k != 13 && (unsigned)nz < VGRID) {
                        unsigned wrd = ((nz >> 5) == wlo) ? wa[rr] : wb[rr];
                        pmask |= ((wrd >> (nz & 31)) & 1u) << k;
                    }
                }
            }
        }
        s_hm[c][q][p] = pmask;
        if (q == 0) {
            s_pk[c][p] = (cx << 16) | (cy << 8) | cz;
            int jc = 0;
            if (i < n) {
                int lin = (cx * VGRID + cy) * VGRID + cz;
                jc = ((unsigned)(e0 >> 32) == (unsigned)lin)
                         ? (int)(unsigned)e0
                         : hwalk(hash, lin, (s0 + 1) & (HSIZE - 1));
            }
            s_jc[c][p] = jc;
        }
    };

    // ---- combine masks; quarter q prefetches rank q ----
    auto combine = [&](int c, int cx, int cy, int cz) {
        unsigned hmc = s_hm[c][0][p] | s_hm[c][1][p] | s_hm[c][2][p] | s_hm[c][3][p];
        if (q == 0) s_hm[c][0][p] = hmc;    // idempotent combine
        unsigned mm = hmc;
#pragma unroll
        for (int d = 0; d < 3; ++d) if (d < q) mm &= mm - 1u;  // drop q lowest
        int ja = 0;
        if (mm) {
            int kA = __builtin_ctz(mm);
            ja = hlookup(hash, ((cx + kA / 9 - 1) * VGRID + (cy + (kA / 3) % 3 - 1))
                               * VGRID + (cz + kA % 3 - 1));
        }
        s_p[c][q][p] = ja;
    };

    // ---- 16-row MFMA group per wave ----
    auto gemm = [&](int c, int base) {
        int row = q * 16 + m;
        unsigned rhm = s_hm[c][0][row];
        int rjc = s_jc[c][row];

        unsigned gor = rhm;   // union over the 16 rows
        gor |= (unsigned)__shfl_xor((int)gor, 1);
        gor |= (unsigned)__shfl_xor((int)gor, 2);
        gor |= (unsigned)__shfl_xor((int)gor, 4);
        gor |= (unsigned)__shfl_xor((int)gor, 8);
        gor = __builtin_amdgcn_readfirstlane(gor);

        float4v acc[4] = {{0,0,0,0},{0,0,0,0},{0,0,0,0},{0,0,0,0}};

        {   // center tap (13)
            short8 a0 = Fp[(size_t)rjc * 8 + quad];
            short8 a1 = Fp[(size_t)rjc * 8 + 4 + quad];
#pragma unroll
            for (int nt = 0; nt < 4; ++nt) {
                short8 b0 = Bp[((13 * 2 + 0) * 4 + quad) * 64 + nt * 16 + m];
                short8 b1 = Bp[((13 * 2 + 1) * 4 + quad) * 64 + nt * 16 + m];
                acc[nt] = __builtin_amdgcn_mfma_f32_16x16x32_bf16(a0, b0, acc[nt], 0, 0, 0);
                acc[nt] = __builtin_amdgcn_mfma_f32_16x16x32_bf16(a1, b1, acc[nt], 0, 0, 0);
            }
        }

        unsigned gm = gor;
        while (gm) {
            int k = (int)__builtin_ctz(gm); gm &= gm - 1u;
            bool has = (rhm >> k) & 1u;
            short8 h0 = {0,0,0,0,0,0,0,0}, h1 = {0,0,0,0,0,0,0,0};
            if (has) {
                int rank = __builtin_popcount(rhm & ((1u << k) - 1u));
                int j2;
                if (rank < 4) {
                    j2 = s_p[c][rank][row];
                } else {
                    int rpk = s_pk[c][row];
                    int rx = (rpk >> 16) & 255, ry = (rpk >> 8) & 255, rz = rpk & 255;
                    j2 = hlookup(hash, ((rx + k / 9 - 1) * VGRID + (ry + (k / 3) % 3 - 1))
                                       * VGRID + (rz + k % 3 - 1));
                }
                h0 = Fp[(size_t)j2 * 8 + quad];
                h1 = Fp[(size_t)j2 * 8 + 4 + quad];
            }
#pragma unroll
            for (int nt = 0; nt < 4; ++nt) {
                short8 b0 = Bp[((k * 2 + 0) * 4 + quad) * 64 + nt * 16 + m];
                short8 b1 = Bp[((k * 2 + 1) * 4 + quad) * 64 + nt * 16 + m];
                acc[nt] = __builtin_amdgcn_mfma_f32_16x16x32_bf16(h0, b0, acc[nt], 0, 0, 0);
                acc[nt] = __builtin_amdgcn_mfma_f32_16x16x32_bf16(h1, b1, acc[nt], 0, 0, 0);
            }
        }

#pragma unroll
        for (int nt = 0; nt < 4; ++nt)
#pragma unroll
            for (int r2 = 0; r2 < 4; ++r2) {
                int orow = base + q * 16 + quad * 4 + r2;
                if (orow < n) out[(size_t)orow * COUT + nt * 16 + m] = acc[nt][r2];
            }
    };

    int base0 = blockIdx.x * BPTS;
    int base1 = (blockIdx.x + gridDim.x) * BPTS;
    int i0 = base0 + p;
    int i1 = base1 + p;

    // chunk 0 probe (exposed once per block)
    int cx0, cy0, cz0; unsigned wa0[3], wb0[3]; unsigned long long e0; unsigned sl0;
    issue(i0, cx0, cy0, cz0, wa0, wb0, e0, sl0);
    finish(0, i0, cx0, cy0, cz0, wa0, wb0, e0, sl0);
    __syncthreads();

    // chunk 1 loads in flight across chunk-0 rank-prefetch + GEMM
    int cx1, cy1, cz1; unsigned wa1[3], wb1[3]; unsigned long long e1; unsigned sl1;
    issue(i1, cx1, cy1, cz1, wa1, wb1, e1, sl1);

    combine(0, cx0, cy0, cz0);
    __syncthreads();

    gemm(0, base0);

    finish(1, i1, cx1, cy1, cz1, wa1, wb1, e1, sl1);
    __syncthreads();
    combine(1, cx1, cy1, cz1);
    __syncthreads();

    gemm(1, base1);
}

extern "C" void kernel_launch(void* const* d_in, const int* in_sizes, int n_in,
                              void* d_out, int out_size, void* d_ws, size_t ws_size,
                              hipStream_t stream) {
    const int* coords = (const int*)d_in[0];
    const float* feats = (const float*)d_in[1];
    const float* weights = (const float*)d_in[2];
    float* out = (float*)d_out;

    int n = in_sizes[0] / 3;  // 262144

    // layout: bits @0 (2 MiB) | hash @2 MiB (8 MiB) | Wt @10 MiB (216 KiB)
    //         | feats_bf @11 MiB (32 MiB)  => 43 MiB total
    char* ws = (char*)d_ws;
    size_t BITMAP_BYTES = (size_t)VGRID * VGRID * VGRID / 8;   // 2 MiB
    unsigned* bits = (unsigned*)ws;
    unsigned long long* hash = (unsigned long long*)(ws + BITMAP_BYTES);
    short* wbft = (short*)(ws + ((size_t)10 << 20));
    short* fb = (short*)(ws + ((size_t)11 << 20));

    // bitmap cleared to 0; hash cleared to 0xFF (= HEMPTY sentinel, also
    // immune to harness poison values)
    hipMemsetAsync(ws, 0, BITMAP_BYTES, stream);
    hipMemsetAsync(ws + BITMAP_BYTES, 0xFF, (size_t)HSIZE * 8, stream);

    int bt_blocks = (n + 255) / 256;
    build_scatter<<<bt_blocks, 256, 0, stream>>>(coords, hash, bits, n);

    int fb_elems = n * CIN;
    int conv_blocks = (fb_elems / 16 + 255) / 256;
    build_convert<<<N_TAPS + conv_blocks, 256, 0, stream>>>(
        weights, wbft, feats, fb, fb_elems);

    int f_blocks = (n + 2 * BPTS - 1) / (2 * BPTS);
    fused_kernel<<<f_blocks, 256, 0, stream>>>(coords, hash, bits, fb, wbft, out, n);
}

// Round 9
// 223.056 us; speedup vs baseline: 1.0718x; 1.0718x over previous
//
#include <hip/hip_runtime.h>

#define VGRID 256
#define N_TAPS 27
#define CIN 64
#define COUT 64
#define BPTS 64      // points per block (1 group of 16 per wave, 4 waves)
#define HBITS 20
#define HSIZE (1u << HBITS)          // 1M slots x 8 B = 8 MiB hash
#define HEMPTY 0xFFFFFFFFFFFFFFFFull // memset 0xFF => empty

typedef short short8 __attribute__((ext_vector_type(8)));   // 8 bf16
typedef float float4v __attribute__((ext_vector_type(4)));  // MFMA C/D + NT loads

__device__ __forceinline__ short f2bf(float x) {
    unsigned u = __builtin_bit_cast(unsigned, x);
    unsigned r = (u + 0x7FFF + ((u >> 16) & 1)) >> 16;  // RNE
    return (short)r;
}

__device__ __forceinline__ unsigned hslot(int lin) {
    return ((unsigned)lin * 2654435761u) >> (32 - HBITS);
}

// lookup for a voxel KNOWN to exist (bitmap-gated)
__device__ __forceinline__ int hlookup(const unsigned long long* __restrict__ hash,
                                       int lin) {
    unsigned s = hslot(lin);
    for (;;) {
        unsigned long long e = hash[s];
        if ((unsigned)(e >> 32) == (unsigned)lin) return (int)(unsigned)e;
        s = (s + 1) & (HSIZE - 1);
    }
}

// Merged build (R6 structure had best residual):
// blocks [0,bt): hash insert + bitmap
// blocks [bt, bt+27): weight conversion to fragment-major bf16
// blocks [bt+27,...): feats f32 -> bf16, 16 floats/thread, NT load+store
__global__ void __launch_bounds__(256) build_kernel(
        const int* __restrict__ coords, unsigned long long* __restrict__ hash,
        unsigned* __restrict__ bits, const float* __restrict__ W,
        short* __restrict__ Wt, const float* __restrict__ F,
        short* __restrict__ Fb, int n, int bt_blocks, int fb_elems) {
    int b = (int)blockIdx.x;
    if (b >= bt_blocks + N_TAPS) {
        int idx = (b - bt_blocks - N_TAPS) * 256 + (int)threadIdx.x;
        int e = idx * 16;
        if (e < fb_elems) {
            const float4v* s = (const float4v*)(F + e);
            float4v x0 = __builtin_nontemporal_load(s);
            float4v x1 = __builtin_nontemporal_load(s + 1);
            float4v x2 = __builtin_nontemporal_load(s + 2);
            float4v x3 = __builtin_nontemporal_load(s + 3);
            short8 o0 = {f2bf(x0[0]), f2bf(x0[1]), f2bf(x0[2]), f2bf(x0[3]),
                         f2bf(x1[0]), f2bf(x1[1]), f2bf(x1[2]), f2bf(x1[3])};
            short8 o1 = {f2bf(x2[0]), f2bf(x2[1]), f2bf(x2[2]), f2bf(x2[3]),
                         f2bf(x3[0]), f2bf(x3[1]), f2bf(x3[2]), f2bf(x3[3])};
            __builtin_nontemporal_store(o0, (short8*)(Fb + e));
            __builtin_nontemporal_store(o1, (short8*)(Fb + e + 8));
        }
        return;
    }
    if (b >= bt_blocks) {
        int tap = b - bt_blocks;
        for (int e = threadIdx.x; e < CIN * COUT; e += 256) {
            int ci = e >> 6, co = e & 63;
            int ks = ci >> 5, quad = (ci >> 3) & 3, el = ci & 7;
            Wt[((((size_t)tap * 2 + ks) * 4 + quad) * 64 + co) * 8 + el] =
                f2bf(W[((size_t)tap * CIN + ci) * COUT + co]);
        }
        return;
    }
    int i = b * 256 + threadIdx.x;
    if (i >= n) return;
    int lin = (coords[i * 3 + 0] * VGRID + coords[i * 3 + 1]) * VGRID + coords[i * 3 + 2];
    // insert (lin -> i); duplicates keep max i (== ref last-write-wins since
    // high words equal, u64 atomicMax compares low words)
    unsigned long long want = ((unsigned long long)(unsigned)lin << 32) | (unsigned)i;
    unsigned s = hslot(lin);
    for (;;) {
        unsigned long long old = atomicCAS(&hash[s], HEMPTY, want);
        if (old == HEMPTY) break;
        if ((unsigned)(old >> 32) == (unsigned)lin) { atomicMax(&hash[s], want); break; }
        s = (s + 1) & (HSIZE - 1);
    }
    atomicOr(&bits[lin >> 5], 1u << (lin & 31));
}

// Gather-formulation conv (R7 structure + depth-2 pipelined tap loop):
// block=256 threads handles 64 points; each wave owns ONE 16-row MFMA group.
// Probe split 4-ways (quarter q: rows 2q..; prefetches ranks q and q+4).
// Tap loop: rotating 2-slot pipeline with a SINGLE resolve body — next tap's
// j-resolve + fragment loads issue BEFORE current tap's MFMAs, so gather
// latency hides under the MFMA+wait of the previous tap. (R6's failure was
// duplicated resolve code, not batching per se.)
__global__ void __launch_bounds__(256) fused_kernel(
        const int* __restrict__ coords, const unsigned long long* __restrict__ hash,
        const unsigned* __restrict__ bits, const short* __restrict__ featsb,
        const short* __restrict__ Wt, float* __restrict__ out, int n) {
    __shared__ int s_pk[BPTS];
    __shared__ unsigned s_hm[4][BPTS];
    __shared__ int s_jc[BPTS];
    __shared__ int s_p[8][BPTS];

    int t = threadIdx.x;
    int p = t & (BPTS - 1);
    int q = t >> 6;                      // quarter == wave index
    int i = blockIdx.x * BPTS + p;

    // ---- phase 1: 4-way split probe ----
    int cx = 0, cy = 0, cz = 0;
    unsigned pmask = 0;
    if (i < n) {
        cx = coords[i * 3 + 0];
        cy = coords[i * 3 + 1];
        cz = coords[i * 3 + 2];
        if (q == 0) s_jc[p] = hlookup(hash, (cx * VGRID + cy) * VGRID + cz);

        int zlo = cz > 0 ? cz - 1 : 0;
        int zhi = cz < VGRID - 1 ? cz + 1 : VGRID - 1;
        int wlo = zlo >> 5, whi = zhi >> 5;
        int nr = (q == 3) ? 3 : 2;       // rows handled by this quarter
        int r0 = 2 * q;
        unsigned rwa[3], rwb[3];
#pragma unroll
        for (int rr = 0; rr < 3; ++rr) {
            int r = r0 + rr;
            int nx = cx + r / 3 - 1, ny = cy + r % 3 - 1;
            bool v = (rr < nr) && ((unsigned)nx < VGRID) && ((unsigned)ny < VGRID);
            int rb = ((nx * VGRID + ny) * VGRID) >> 5;  // row base word (base %32==0)
            rwa[rr] = v ? bits[rb + wlo] : 0u;
            rwb[rr] = v ? bits[rb + whi] : 0u;
        }
#pragma unroll
        for (int rr = 0; rr < 3; ++rr) {
            int r = r0 + rr;
#pragma unroll
            for (int zz = 0; zz < 3; ++zz) {
                int k = r * 3 + zz;
                int nz = cz + zz - 1;
                if (rr < nr && k != 13 && (unsigned)nz < VGRID) {
                    unsigned wrd = ((nz >> 5) == wlo) ? rwa[rr] : rwb[rr];
                    pmask |= ((wrd >> (nz & 31)) & 1u) << k;
                }
            }
        }
    }
    if (q == 0) {
        s_pk[p] = (cx << 16) | (cy << 8) | cz;
        if (i >= n) s_jc[p] = 0;
    }
    s_hm[q][p] = pmask;
    __syncthreads();

    // ---- phase 2: combine masks; quarter q prefetches ranks q and q+4 ----
    {
        unsigned hmc = s_hm[0][p] | s_hm[1][p] | s_hm[2][p] | s_hm[3][p];
        if (q == 0) s_hm[0][p] = hmc;    // idempotent combine
        unsigned mm = hmc;
#pragma unroll
        for (int d = 0; d < 3; ++d) if (d < q) mm &= mm - 1u;  // rank q at head
        int ja = 0, jb = 0;
        if (mm) {
            int kA = __builtin_ctz(mm);
            ja = hlookup(hash, ((cx + kA / 9 - 1) * VGRID + (cy + (kA / 3) % 3 - 1))
                               * VGRID + (cz + kA % 3 - 1));
            unsigned mm2 = mm;           // drop 4 -> rank q+4 at head
            mm2 &= mm2 - 1u; if (mm2) mm2 &= mm2 - 1u;
            if (mm2) mm2 &= mm2 - 1u; if (mm2) mm2 &= mm2 - 1u;
            if (mm2) {
                int kB = __builtin_ctz(mm2);
                jb = hlookup(hash, ((cx + kB / 9 - 1) * VGRID + (cy + (kB / 3) % 3 - 1))
                                   * VGRID + (cz + kB % 3 - 1));
            }
        }
        s_p[q][p] = ja;
        s_p[q + 4][p] = jb;
    }
    __syncthreads();

    // ---- phase 3: GEMM, one 16-row group per wave, pipelined tap loop ----
    int lane = t & 63;
    int m = lane & 15, quad = lane >> 4;
    const short8* Bp = (const short8*)Wt;
    const short8* Fp = (const short8*)featsb;   // 16B units; row j = 8 units
    int base = blockIdx.x * BPTS;

    int row = q * 16 + m;
    unsigned rhm = s_hm[0][row];
    int rjc = s_jc[row];

    // slot A = center tap: loads issue immediately (before gor reduce)
    int kA = 13;
    short8 fA0 = Fp[(size_t)rjc * 8 + quad];
    short8 fA1 = Fp[(size_t)rjc * 8 + 4 + quad];

    unsigned gor = rhm;   // union over the 16 rows (quads hold same rows)
    gor |= (unsigned)__shfl_xor((int)gor, 1);
    gor |= (unsigned)__shfl_xor((int)gor, 2);
    gor |= (unsigned)__shfl_xor((int)gor, 4);
    gor |= (unsigned)__shfl_xor((int)gor, 8);
    gor = __builtin_amdgcn_readfirstlane(gor);

    float4v acc[4] = {{0,0,0,0},{0,0,0,0},{0,0,0,0},{0,0,0,0}};

    unsigned gm = gor;
    while (kA >= 0) {
        // resolve + issue next tap into slot B (single resolve body)
        int kB = -1;
        short8 fB0 = {0,0,0,0,0,0,0,0}, fB1 = {0,0,0,0,0,0,0,0};
        if (gm) {
            kB = (int)__builtin_ctz(gm); gm &= gm - 1u;
            if ((rhm >> kB) & 1u) {
                int rank = __builtin_popcount(rhm & ((1u << kB) - 1u));
                int j2;
                if (rank < 8) {
                    j2 = s_p[rank][row];         // dynamic LDS index, not regs
                } else {                          // P ~ 1e-4: hash fallback
                    int rpk = s_pk[row];
                    int rx = (rpk >> 16) & 255, ry = (rpk >> 8) & 255, rz = rpk & 255;
                    j2 = hlookup(hash, ((rx + kB / 9 - 1) * VGRID
                                        + (ry + (kB / 3) % 3 - 1)) * VGRID
                                       + (rz + kB % 3 - 1));
                }
                fB0 = Fp[(size_t)j2 * 8 + quad];
                fB1 = Fp[(size_t)j2 * 8 + 4 + quad];
            }
        }
        // MFMA slot A (waits only on fA; fB stays in flight)
#pragma unroll
        for (int nt = 0; nt < 4; ++nt) {
            short8 b0 = Bp[((kA * 2 + 0) * 4 + quad) * 64 + nt * 16 + m];
            short8 b1 = Bp[((kA * 2 + 1) * 4 + quad) * 64 + nt * 16 + m];
            acc[nt] = __builtin_amdgcn_mfma_f32_16x16x32_bf16(fA0, b0, acc[nt], 0, 0, 0);
            acc[nt] = __builtin_amdgcn_mfma_f32_16x16x32_bf16(fA1, b1, acc[nt], 0, 0, 0);
        }
        kA = kB; fA0 = fB0; fA1 = fB1;   // rotate
    }

    // store 16x64 tile, written exactly once; regular stores (L2 assembles
    // full lines -> WRITE_SIZE == output size)
#pragma unroll
    for (int nt = 0; nt < 4; ++nt)
#pragma unroll
        for (int r2 = 0; r2 < 4; ++r2) {
            int orow = base + q * 16 + quad * 4 + r2;
            if (orow < n) out[(size_t)orow * COUT + nt * 16 + m] = acc[nt][r2];
        }
}

extern "C" void kernel_launch(void* const* d_in, const int* in_sizes, int n_in,
                              void* d_out, int out_size, void* d_ws, size_t ws_size,
                              hipStream_t stream) {
    const int* coords = (const int*)d_in[0];
    const float* feats = (const float*)d_in[1];
    const float* weights = (const float*)d_in[2];
    float* out = (float*)d_out;

    int n = in_sizes[0] / 3;  // 262144

    // layout: bits @0 (2 MiB) | hash @2 MiB (8 MiB) | Wt @10 MiB (216 KiB)
    //         | feats_bf @11 MiB (32 MiB)  => 43 MiB total
    char* ws = (char*)d_ws;
    size_t BITMAP_BYTES = (size_t)VGRID * VGRID * VGRID / 8;   // 2 MiB
    unsigned* bits = (unsigned*)ws;
    unsigned long long* hash = (unsigned long long*)(ws + BITMAP_BYTES);
    short* wbft = (short*)(ws + ((size_t)10 << 20));
    short* fb = (short*)(ws + ((size_t)11 << 20));

    // bitmap cleared to 0; hash cleared to 0xFF (= HEMPTY sentinel, also
    // immune to harness poison values)
    hipMemsetAsync(ws, 0, BITMAP_BYTES, stream);
    hipMemsetAsync(ws + BITMAP_BYTES, 0xFF, (size_t)HSIZE * 8, stream);

    int bt_blocks = (n + 255) / 256;
    int fb_elems = n * CIN;
    int conv_blocks = (fb_elems / 16 + 255) / 256;
    build_kernel<<<bt_blocks + N_TAPS + conv_blocks, 256, 0, stream>>>(
        coords, hash, bits, weights, wbft, feats, fb, n, bt_blocks, fb_elems);

    int f_blocks = (n + BPTS - 1) / BPTS;
    fused_kernel<<<f_blocks, 256, 0, stream>>>(coords, hash, bits, fb, wbft, out, n);
}